// Round 12
// baseline (496.222 us; speedup 1.0000x reference)
//
#include <hip/hip_runtime.h>
#include <math.h>

#define NN 10000
#define NE 320000
#define KS 10
#define CC 32
#define GG 8
#define NTAB 2048
#define TROW 320
#define RMAXf 5.0f
#define AVGf 32.0f

// ---- workspace layout (float offsets) ----
#define OF_TAB 0
#define SZ_TAB ((NTAB + 1) * TROW)
#define OF_GEO (OF_TAB + SZ_TAB)      /* float4-aligned */
#define OF_SND (OF_GEO + 4 * NE)
#define OF_SPK (OF_SND + NE)
#define OF_RCSR (OF_SPK + NE)
#define OF_YE (OF_RCSR + NE)          /* 16 per edge, float4-aligned */
#define OF_SC1 (OF_YE + 16 * NE)
#define OF_SP (OF_SC1 + KS * CC)
#define OF_GV (OF_SP + NN)            /* CSR-ordered gvec */
#define OF_A0 (OF_GV + 3 * NE)
#define OF_NF1 (OF_A0 + NN * CC)
#define OF_SCAL2 (OF_NF1 + NN * CC)
#define OF_NEP (OF_SCAL2 + NN * CC)
#define OF_GM2T (OF_NEP + NN)
#define OF_GNF1P (OF_GM2T + NN * CC * 16)
#define OF_GS1 (OF_GNF1P + NN * CC)
#define OF_ROWS (OF_GS1 + NN * CC)
// zero-init block:
#define OF_DEG (OF_ROWS + NN + 1)
#define OF_CUR (OF_DEG + NN)
#define OF_GSC2 (OF_CUR + NN)
#define OF_END (OF_GSC2 + NN * CC)

__device__ __forceinline__ int lm_of(int m) { return (m == 0) ? 0 : (m < 4) ? 1 : (m < 9) ? 2 : 3; }

__device__ __forceinline__ void sph16(float x, float y, float z, float* Y) {
    const float s3 = 1.7320508075688772f, s5 = 2.23606797749979f, s15 = 3.872983346207417f,
                s105 = 10.246950765959598f, s358 = 2.091650066335189f,
                s218 = 1.6201851746019651f, s7 = 2.6457513110645907f;
    Y[0] = 1.f;
    Y[1] = s3 * x; Y[2] = s3 * y; Y[3] = s3 * z;
    Y[4] = s15 * x * y; Y[5] = s15 * y * z; Y[6] = 0.5f * s5 * (3.f * z * z - 1.f);
    Y[7] = s15 * x * z; Y[8] = 0.5f * s15 * (x * x - y * y);
    Y[9] = s358 * y * (3.f * x * x - y * y);
    Y[10] = s105 * x * y * z;
    Y[11] = s218 * y * (5.f * z * z - 1.f);
    Y[12] = 0.5f * s7 * z * (5.f * z * z - 3.f);
    Y[13] = s218 * x * (5.f * z * z - 1.f);
    Y[14] = 0.5f * s105 * z * (x * x - y * y);
    Y[15] = s358 * x * (x * x - 3.f * y * y);
}

__device__ __forceinline__ void sph16_grad(float x, float y, float z, float* Dx, float* Dy, float* Dz) {
    const float s3 = 1.7320508075688772f, s5 = 2.23606797749979f, s15 = 3.872983346207417f,
                s105 = 10.246950765959598f, s358 = 2.091650066335189f,
                s218 = 1.6201851746019651f, s7 = 2.6457513110645907f;
    Dx[0] = 0; Dy[0] = 0; Dz[0] = 0;
    Dx[1] = s3; Dy[1] = 0; Dz[1] = 0;
    Dx[2] = 0; Dy[2] = s3; Dz[2] = 0;
    Dx[3] = 0; Dy[3] = 0; Dz[3] = s3;
    Dx[4] = s15 * y; Dy[4] = s15 * x; Dz[4] = 0;
    Dx[5] = 0; Dy[5] = s15 * z; Dz[5] = s15 * y;
    Dx[6] = 0; Dy[6] = 0; Dz[6] = 3.f * s5 * z;
    Dx[7] = s15 * z; Dy[7] = 0; Dz[7] = s15 * x;
    Dx[8] = s15 * x; Dy[8] = -s15 * y; Dz[8] = 0;
    Dx[9] = 6.f * s358 * x * y; Dy[9] = 3.f * s358 * (x * x - y * y); Dz[9] = 0;
    Dx[10] = s105 * y * z; Dy[10] = s105 * x * z; Dz[10] = s105 * x * y;
    Dx[11] = 0; Dy[11] = s218 * (5.f * z * z - 1.f); Dz[11] = 10.f * s218 * y * z;
    Dx[12] = 0; Dy[12] = 0; Dz[12] = 0.5f * s7 * (15.f * z * z - 3.f);
    Dx[13] = s218 * (5.f * z * z - 1.f); Dy[13] = 0; Dz[13] = 10.f * s218 * x * z;
    Dx[14] = s105 * x * z; Dy[14] = -s105 * y * z; Dz[14] = 0.5f * s105 * (x * x - y * y);
    Dx[15] = 3.f * s358 * (x * x - y * y); Dy[15] = -6.f * s358 * x * y; Dz[15] = 0;
}

// -------- species argmax --------
__global__ void k_species(const float* __restrict__ na, int* __restrict__ sp) {
    int n = blockIdx.x * blockDim.x + threadIdx.x;
    if (n >= NN) return;
    int k = 0;
    for (int j = 0; j < KS; j++)
        if (na[n * KS + j] > 0.5f) k = j;
    sp[n] = k;
}

// -------- scal1 table = W_emb @ Wup1 --------
__global__ void k_scal1(const float* __restrict__ Wemb, const float* __restrict__ Wup1, float* __restrict__ st) {
    int i = threadIdx.x;
    if (i >= KS * CC) return;
    int k = i / CC, c = i % CC;
    float s = 0;
    for (int j = 0; j < CC; j++) s += Wemb[k * CC + j] * Wup1[j * CC + c];
    st[i] = s;
}

// -------- radial MLP lookup table (values + d/dr), fp32 MLP (fp64 radial seed) --------
__global__ void k_table(const float* __restrict__ M1a, const float* __restrict__ M1b,
                        const float* __restrict__ M1c, const float* __restrict__ M1d,
                        const float* __restrict__ M2a, const float* __restrict__ M2b,
                        const float* __restrict__ M2c, const float* __restrict__ M2d,
                        float* __restrict__ tab) {
    const double PI = 3.14159265358979323846;
    int row = blockIdx.x;
    int j = threadIdx.x;  // 0..63
    __shared__ float sR[8], sdR[8];
    __shared__ float sA[64], sdA[64], sB[64], sdB[64];
    if (j < 8) {
        double r = (double)row * ((double)RMAXf / NTAB);
        if (r < 1e-6) r = 1e-6;
        double a = (double)(j + 1) * PI / (double)RMAXf;
        double env = 0.0, denv = 0.0;
        if (row < NTAB) {
            double t = r / (double)RMAXf;
            double t4 = t * t * t * t;
            env = 1.0 - 21.0 * t4 * t + 35.0 * t4 * t * t - 15.0 * t4 * t * t * t;
            denv = (-105.0 * t4 + 210.0 * t4 * t - 105.0 * t4 * t * t) / (double)RMAXf;
        }
        double pref = sqrt(2.0 / (double)RMAXf);
        double s = sin(a * r), cg = cos(a * r);
        double bess = pref * s / r;
        double dbess = pref * (a * cg / r - s / (r * r));
        sR[j] = (float)(bess * env);
        sdR[j] = (float)(dbess * env + bess * denv);
    }
    __syncthreads();
    size_t rb = (size_t)row * TROW;

    // ---- MLP1 ----
    {
        float p = 0, dp = 0;
        for (int i = 0; i < 8; i++) { float w = M1a[i * 64 + j]; p += sR[i] * w; dp += sdR[i] * w; }
        float sg = 1.f / (1.f + expf(-p));
        sB[j] = p * sg; sdB[j] = dp * sg * (1.f + p * (1.f - sg));
    }
    __syncthreads();
    {
        float p = 0, dp = 0;
        for (int i = 0; i < 64; i++) { float w = M1b[i * 64 + j]; p += sB[i] * w; dp += sdB[i] * w; }
        float sg = 1.f / (1.f + expf(-p));
        sA[j] = p * sg; sdA[j] = dp * sg * (1.f + p * (1.f - sg));
    }
    __syncthreads();
    {
        float p = 0, dp = 0;
        for (int i = 0; i < 64; i++) { float w = M1c[i * 64 + j]; p += sA[i] * w; dp += sdA[i] * w; }
        float sg = 1.f / (1.f + expf(-p));
        sB[j] = p * sg; sdB[j] = dp * sg * (1.f + p * (1.f - sg));
    }
    __syncthreads();
    #pragma unroll
    for (int t2 = 0; t2 < 2; t2++) {
        int o = j + t2 * 64;
        if ((o & 3) == 0) {
            float p = 0, dp = 0;
            for (int i = 0; i < 64; i++) { float w = M1d[i * 128 + o]; p += sB[i] * w; dp += sdB[i] * w; }
            int c = o >> 2;
            tab[rb + c] = p;
            tab[rb + 32 + c] = dp;
        }
    }
    __syncthreads();

    // ---- MLP2 ----
    {
        float p = 0, dp = 0;
        for (int i = 0; i < 8; i++) { float w = M2a[i * 64 + j]; p += sR[i] * w; dp += sdR[i] * w; }
        float sg = 1.f / (1.f + expf(-p));
        sB[j] = p * sg; sdB[j] = dp * sg * (1.f + p * (1.f - sg));
    }
    __syncthreads();
    {
        float p = 0, dp = 0;
        for (int i = 0; i < 64; i++) { float w = M2b[i * 64 + j]; p += sB[i] * w; dp += sdB[i] * w; }
        float sg = 1.f / (1.f + expf(-p));
        sA[j] = p * sg; sdA[j] = dp * sg * (1.f + p * (1.f - sg));
    }
    __syncthreads();
    {
        float p = 0, dp = 0;
        for (int i = 0; i < 64; i++) { float w = M2c[i * 64 + j]; p += sA[i] * w; dp += sdA[i] * w; }
        float sg = 1.f / (1.f + expf(-p));
        sB[j] = p * sg; sdB[j] = dp * sg * (1.f + p * (1.f - sg));
    }
    __syncthreads();
    #pragma unroll
    for (int t2 = 0; t2 < 2; t2++) {
        int o = j + t2 * 64;
        float p = 0, dp = 0;
        for (int i = 0; i < 64; i++) { float w = M2d[i * 128 + o]; p += sB[i] * w; dp += sdB[i] * w; }
        tab[rb + 64 + o] = p;
        tab[rb + 192 + o] = dp;
    }
}

// -------- rcv degree count only --------
__global__ void k_deg(const int* __restrict__ ei, int* __restrict__ deg) {
    int e = blockIdx.x * 256 + threadIdx.x;
    if (e >= NE) return;
    atomicAdd(&deg[ei[NE + e]], 1);
}

// -------- exclusive scan over NN degree counters (single block, 1024 thr) --------
__global__ void k_scan(const int* __restrict__ deg, int* __restrict__ rows, int* __restrict__ cur) {
    __shared__ int part[1024];
    int t = threadIdx.x;
    const int per = (NN + 1023) / 1024;
    int base = t * per;
    int s = 0;
    for (int i = 0; i < per; i++) {
        int idx = base + i;
        if (idx < NN) s += deg[idx];
    }
    part[t] = s;
    __syncthreads();
    for (int off = 1; off < 1024; off <<= 1) {
        int v = (t >= off) ? part[t - off] : 0;
        __syncthreads();
        part[t] += v;
        __syncthreads();
    }
    int run = (t == 0) ? 0 : part[t - 1];
    for (int i = 0; i < per; i++) {
        int idx = base + i;
        if (idx < NN) {
            rows[idx] = run;
            cur[idx] = run;
            run += deg[idx];
        }
    }
    if (t == 1023) rows[NN] = run;
}

// -------- CSR fill: geometry + packed edge data + per-edge spherical harmonics --------
__global__ void k_fill(const float* __restrict__ pos, const float* __restrict__ shifts,
                       const int* __restrict__ ei, const int* __restrict__ sp,
                       int* __restrict__ cur, int* __restrict__ snd, int* __restrict__ spk,
                       float* __restrict__ rcsr, float4* __restrict__ geo,
                       float* __restrict__ YE) {
    int e = blockIdx.x * 256 + threadIdx.x;
    if (e >= NE) return;
    int s = ei[e], t = ei[NE + e];
    float vx = pos[3 * t] - pos[3 * s] + shifts[3 * e];
    float vy = pos[3 * t + 1] - pos[3 * s + 1] + shifts[3 * e + 1];
    float vz = pos[3 * t + 2] - pos[3 * s + 2] + shifts[3 * e + 2];
    float r = sqrtf(vx * vx + vy * vy + vz * vz + 1e-12f);
    float inv = 1.f / r;
    float ux = vx * inv, uy = vy * inv, uz = vz * inv;
    int p = atomicAdd(&cur[t], 1);
    snd[p] = s;
    spk[p] = sp[s];
    rcsr[p] = r;
    geo[p] = make_float4(r, ux, uy, uz);
    float Y[16];
    sph16(ux, uy, uz, Y);
    float4* yp = (float4*)&YE[(size_t)p * 16];
    yp[0] = make_float4(Y[0], Y[1], Y[2], Y[3]);
    yp[1] = make_float4(Y[4], Y[5], Y[6], Y[7]);
    yp[2] = make_float4(Y[8], Y[9], Y[10], Y[11]);
    yp[3] = make_float4(Y[12], Y[13], Y[14], Y[15]);
}

// -------- layer-1 gather + node mid: one block (4 waves, 8 streams) per node --------
__global__ __launch_bounds__(256, 4)
void k_gather1(const int* __restrict__ rows, const int* __restrict__ spk,
               const float* __restrict__ rcsr, const int* __restrict__ sp,
               const float* __restrict__ sc1, const float* __restrict__ tab,
               const float* __restrict__ Wl1, const float* __restrict__ Wprod1,
               const float* __restrict__ Wup2, const float* __restrict__ wr1,
               const float* __restrict__ aE,
               float* __restrict__ a0s, float* __restrict__ nf1,
               float* __restrict__ scal2, float* __restrict__ nep) {
    __shared__ float red[4][CC];
    int wid = blockIdx.x;
    int tid = threadIdx.x;
    int wv = tid >> 6, lane = tid & 63, c = lane & 31, h = lane >> 5, hb = h << 5;
    int stream = wv * 2 + h;
    int r0 = rows[wid], dg = rows[wid + 1] - r0;
    float acc = 0.f;
    for (int j = stream; j < dg; j += 8) {
        int p = r0 + j;
        float r = rcsr[p];
        float scv = sc1[spk[p] * CC + c];
        float w1 = 0.f;
        if (r < RMAXf) {
            float tt = r * (NTAB / RMAXf);
            int i = (int)tt; if (i > NTAB - 1) i = NTAB - 1;
            float f = tt - (float)i;
            size_t b = (size_t)i * TROW + c;
            w1 = tab[b] * (1.f - f) + tab[b + TROW] * f;
        }
        acc += scv * w1;
    }
    acc += __shfl_xor(acc, 32, 64);
    if (h == 0) red[wv][c] = acc;
    __syncthreads();
    if (wv != 0) return;
    acc = red[0][c] + red[1][c] + red[2][c] + red[3][c];
    float a0 = 0.f;
    for (int d = 0; d < CC; d++) a0 += __shfl(acc, hb + d, 64) * Wl1[d * CC + c];
    a0 *= (1.f / AVGf);
    int k = sp[wid];
    const float* cp = &Wprod1[(k * CC + c) * 3];
    float nf = a0 * (cp[0] + cp[1] * a0 + cp[2] * a0 * a0);
    float s2 = 0.f;
    for (int d = 0; d < CC; d++) s2 += __shfl(nf, hb + d, 64) * Wup2[d * CC + c];
    float t1 = nf * wr1[c];
    for (int m = 16; m >= 1; m >>= 1) t1 += __shfl_xor(t1, m, 64);
    if (h == 0) {
        a0s[wid * CC + c] = a0;
        nf1[wid * CC + c] = nf;
        scal2[wid * CC + c] = s2;
        if (c == 0) nep[wid] = aE[k] + t1;
    }
}

// -------- layer-2 gather + node phase split across 4 waves --------
__global__ __launch_bounds__(256, 4)
void k_node2(const int* __restrict__ rows, const int* __restrict__ snd,
             const float* __restrict__ rcsr, const float* __restrict__ YE,
             const int* __restrict__ sp,
             const float* __restrict__ scal2, const float* __restrict__ tab,
             const float* __restrict__ Wl2, const float* __restrict__ Wprod2,
             const float* __restrict__ Wsc2, const float* __restrict__ nf1,
             const float* __restrict__ Wr2a, const float* __restrict__ wr2b,
             const float* __restrict__ wr1, const float* __restrict__ nep,
             const int* __restrict__ batch,
             float* __restrict__ gm2T, float* __restrict__ gnf1p,
             float* __restrict__ out_total, float* __restrict__ out_ne) {
    __shared__ float ldsS[4][512];
    __shared__ float ldsA[512];
    __shared__ float ldsT[512];
    __shared__ float ldsG[CC];
    int wid = blockIdx.x;
    int tid = threadIdx.x;
    int wv = tid >> 6, lane = tid & 63, c = lane & 31, h = lane >> 5, hb = h << 5;
    int stream = wv * 2 + h;
    int r0 = rows[wid], dg = rows[wid + 1] - r0;

    // ---- pass 1: S2 gather across 8 streams (Y from YE) ----
    float S2r[16];
    #pragma unroll
    for (int m = 0; m < 16; m++) S2r[m] = 0.f;
    for (int j = stream; j < dg; j += 8) {
        int p = r0 + j;
        float r = rcsr[p];
        float sc = scal2[snd[p] * CC + c];
        float scw[4] = {0, 0, 0, 0};
        if (r < RMAXf) {
            float tt = r * (NTAB / RMAXf);
            int i = (int)tt; if (i > NTAB - 1) i = NTAB - 1;
            float f = tt - (float)i;
            size_t b = (size_t)i * TROW + 64 + c * 4;
            float4 t0 = *(const float4*)&tab[b];
            float4 t1 = *(const float4*)&tab[b + TROW];
            scw[0] = sc * (t0.x + (t1.x - t0.x) * f);
            scw[1] = sc * (t0.y + (t1.y - t0.y) * f);
            scw[2] = sc * (t0.z + (t1.z - t0.z) * f);
            scw[3] = sc * (t0.w + (t1.w - t0.w) * f);
        }
        const float4* yp = (const float4*)&YE[(size_t)p * 16];
        float4 y0 = yp[0], y1 = yp[1], y2 = yp[2], y3 = yp[3];
        float Y[16] = {y0.x, y0.y, y0.z, y0.w, y1.x, y1.y, y1.z, y1.w,
                       y2.x, y2.y, y2.z, y2.w, y3.x, y3.y, y3.z, y3.w};
        #pragma unroll
        for (int m = 0; m < 16; m++) S2r[m] += scw[lm_of(m)] * Y[m];
    }
    #pragma unroll
    for (int m = 0; m < 16; m++) S2r[m] += __shfl_xor(S2r[m], 32, 64);
    if (h == 0) {
        #pragma unroll
        for (int m = 0; m < 16; m++) ldsS[wv][m * 32 + c] = S2r[m];
    }
    __syncthreads();
    for (int idx = tid; idx < 512; idx += 256)
        ldsS[0][idx] += ldsS[1][idx] + ldsS[2][idx] + ldsS[3][idx];
    __syncthreads();

    // ---- A2: each wave computes 4 of the 16 m's ----
    int d = c;
    int k = sp[wid];
    const float* c2 = &Wprod2[(k * CC + d) * 4];
    #pragma unroll
    for (int mi = 0; mi < 4; mi++) {
        int m = wv * 4 + mi;
        const float* wl = &Wl2[lm_of(m) * CC * CC];
        float acc = 0;
        for (int cc = 0; cc < CC; cc++) acc += ldsS[0][m * 32 + cc] * wl[cc * CC + d];
        if (h == 0) ldsA[m * 32 + d] = acc * (1.f / AVGf);
    }
    __syncthreads();

    // ---- wave 0: pl, nf2, energy, gn, g1 ----
    if (wv == 0) {
        float pl[4] = {0, 0, 0, 0};
        #pragma unroll
        for (int m = 0; m < 16; m++) { float a = ldsA[m * 32 + d]; pl[lm_of(m)] += a * a; }
        float nf2 = c2[0] * pl[0] + c2[1] * pl[1] + c2[2] * pl[2] + c2[3] * pl[3];
        for (int cc = 0; cc < CC; cc++) nf2 += nf1[wid * CC + cc] * Wsc2[((size_t)k * CC + cc) * CC + d];
        int jj = d & 15;
        float zj = 0;
        for (int dd = 0; dd < CC; dd++) zj += __shfl(nf2, hb + dd, 64) * Wr2a[dd * 16 + jj];
        float sg = 1.f / (1.f + expf(-zj));
        float e2p = (d < 16) ? zj * sg * wr2b[jj] : 0.f;
        float red = e2p;
        for (int m = 16; m >= 1; m >>= 1) red += __shfl_xor(red, m, 64);
        if (h == 0 && d == 0) {
            float ne = nep[wid] + red;
            out_ne[wid] = ne;
            atomicAdd(&out_total[batch[wid]], ne);
        }
        float gz = sg * (1.f + zj * (1.f - sg)) * wr2b[jj];
        float gn = 0;
        for (int j2 = 0; j2 < 16; j2++) gn += Wr2a[d * 16 + j2] * __shfl(gz, hb + j2, 64);
        if (h == 0) ldsG[d] = gn;
        float g1 = wr1[c];
        for (int dd = 0; dd < CC; dd++) g1 += __shfl(gn, hb + dd, 64) * Wsc2[((size_t)k * CC + c) * CC + dd];
        if (h == 0) gnf1p[wid * CC + c] = g1;
    }
    __syncthreads();

    // ---- T[m][d] = 2*A2*gn*c2 (each wave its 4 m's) ----
    #pragma unroll
    for (int mi = 0; mi < 4; mi++) {
        int m = wv * 4 + mi;
        if (h == 0) ldsT[m * 32 + d] = 2.f * ldsA[m * 32 + d] * ldsG[d] * c2[lm_of(m)];
    }
    __syncthreads();

    // ---- gm[m][c] (each wave its 4 m's; coalesced [m][c] layout) ----
    #pragma unroll
    for (int mi = 0; mi < 4; mi++) {
        int m = wv * 4 + mi;
        const float* wl = &Wl2[lm_of(m) * CC * CC + c * CC];
        float acc = 0;
        for (int dd = 0; dd < CC; dd++) acc += ldsT[m * 32 + dd] * wl[dd];
        if (h == 0) gm2T[(size_t)wid * 512 + m * 32 + c] = acc * (1.f / AVGf);
    }
}

// -------- layer-2 backward gather: 2 blocks/node, 16 streams --------
__global__ __launch_bounds__(256, 4)
void k_gbwd2(const int* __restrict__ rows, const int* __restrict__ snd,
             const float4* __restrict__ geo, const float* __restrict__ YE,
             const float* __restrict__ scal2, const float* __restrict__ tab,
             const float* __restrict__ gm2T,
             float* __restrict__ gsc2, float* __restrict__ gvcsr) {
    int blk = blockIdx.x;
    int wid = blk >> 1, half = blk & 1;
    int tid = threadIdx.x;
    int wv = tid >> 6, lane = tid & 63, c = lane & 31, h = lane >> 5;
    int stream = half * 8 + wv * 2 + h;
    float gm[16];
    #pragma unroll
    for (int m = 0; m < 16; m++) gm[m] = gm2T[(size_t)wid * 512 + m * 32 + c];
    int r0 = rows[wid], dg = rows[wid + 1] - r0;
    for (int j = stream; j < dg; j += 16) {
        int p = r0 + j;
        float4 g4 = geo[p];
        int s = snd[p];
        float sc = scal2[s * CC + c];
        float r = g4.x, ux = g4.y, uy = g4.z, uz = g4.w;
        float w2[4] = {0, 0, 0, 0}, scw[4] = {0, 0, 0, 0}, sdw[4] = {0, 0, 0, 0};
        if (r < RMAXf) {
            float tt = r * (NTAB / RMAXf);
            int i = (int)tt; if (i > NTAB - 1) i = NTAB - 1;
            float f = tt - (float)i;
            size_t b = (size_t)i * TROW + 64 + c * 4;
            size_t b2 = (size_t)i * TROW + 192 + c * 4;
            float4 t0 = *(const float4*)&tab[b];
            float4 t1 = *(const float4*)&tab[b + TROW];
            float4 d0 = *(const float4*)&tab[b2];
            float4 d1 = *(const float4*)&tab[b2 + TROW];
            w2[0] = t0.x + (t1.x - t0.x) * f; w2[1] = t0.y + (t1.y - t0.y) * f;
            w2[2] = t0.z + (t1.z - t0.z) * f; w2[3] = t0.w + (t1.w - t0.w) * f;
            sdw[0] = sc * (d0.x + (d1.x - d0.x) * f); sdw[1] = sc * (d0.y + (d1.y - d0.y) * f);
            sdw[2] = sc * (d0.z + (d1.z - d0.z) * f); sdw[3] = sc * (d0.w + (d1.w - d0.w) * f);
            scw[0] = sc * w2[0]; scw[1] = sc * w2[1]; scw[2] = sc * w2[2]; scw[3] = sc * w2[3];
        }
        const float4* yp = (const float4*)&YE[(size_t)p * 16];
        float4 y0 = yp[0], y1 = yp[1], y2 = yp[2], y3 = yp[3];
        float Y[16] = {y0.x, y0.y, y0.z, y0.w, y1.x, y1.y, y1.z, y1.w,
                       y2.x, y2.y, y2.z, y2.w, y3.x, y3.y, y3.z, y3.w};
        float Dx[16], Dy[16], Dz[16];
        sph16_grad(ux, uy, uz, Dx, Dy, Dz);
        float gsc = 0, gdr = 0, gx = 0, gy = 0, gz = 0;
        #pragma unroll
        for (int m = 0; m < 16; m++) {
            float g = gm[m];
            int l = lm_of(m);
            float t = g * Y[m];
            gsc += t * w2[l];
            gdr += t * sdw[l];
            float gY = g * scw[l];
            gx += gY * Dx[m]; gy += gY * Dy[m]; gz += gY * Dz[m];
        }
        atomicAdd(&gsc2[s * CC + c], gsc);
        for (int m2 = 16; m2 >= 1; m2 >>= 1) {
            gdr += __shfl_xor(gdr, m2, 64);
            gx += __shfl_xor(gx, m2, 64);
            gy += __shfl_xor(gy, m2, 64);
            gz += __shfl_xor(gz, m2, 64);
        }
        if (c == 0) {
            float inv = 1.f / r;
            float dot = ux * gx + uy * gy + uz * gz;
            gvcsr[3 * p] = ux * gdr + (gx - ux * dot) * inv;
            gvcsr[3 * p + 1] = uy * gdr + (gy - uy * dot) * inv;
            gvcsr[3 * p + 2] = uz * gdr + (gz - uz * dot) * inv;
        }
    }
}

// -------- node bwd2: g_S1 --------
__global__ void k_node_bwd2(const float* __restrict__ gnf1p, const float* __restrict__ gsc2,
                            const float* __restrict__ Wup2, const float* __restrict__ a0s,
                            const int* __restrict__ sp, const float* __restrict__ Wprod1,
                            const float* __restrict__ Wl1, float* __restrict__ gS1) {
    int gid = blockIdx.x * 256 + threadIdx.x;
    int n = gid >> 5, c = gid & 31;
    if (n >= NN) return;
    int hb = threadIdx.x & 32;
    float g1 = gnf1p[n * CC + c];
    for (int dd = 0; dd < CC; dd++) g1 += gsc2[n * CC + dd] * Wup2[c * CC + dd];
    float a0 = a0s[n * CC + c];
    int k = sp[n];
    const float* cp = &Wprod1[(k * CC + c) * 3];
    float ga0 = g1 * (cp[0] + 2.f * cp[1] * a0 + 3.f * cp[2] * a0 * a0);
    float acc = 0;
    for (int dd = 0; dd < CC; dd++) acc += __shfl(ga0, hb + dd, 64) * Wl1[c * CC + dd];
    gS1[n * CC + c] = acc * (1.f / AVGf);
}

// -------- layer-1 backward gather + force scatter: 2 blocks/node, 16 streams --------
__global__ __launch_bounds__(256, 4)
void k_gbwd1(const int* __restrict__ rows, const int* __restrict__ snd,
             const int* __restrict__ spk, const float* __restrict__ rcsr,
             const float4* __restrict__ geo, const float* __restrict__ sc1,
             const float* __restrict__ tab, const float* __restrict__ gS1,
             const float* __restrict__ gvcsr, float* __restrict__ F) {
    int blk = blockIdx.x;
    int wid = blk >> 1, half = blk & 1;
    int tid = threadIdx.x;
    int wv = tid >> 6, lane = tid & 63, c = lane & 31, h = lane >> 5;
    int stream = half * 8 + wv * 2 + h;
    int r0 = rows[wid], dg = rows[wid + 1] - r0;
    float gst = gS1[wid * CC + c];
    float ft = 0.f;
    for (int j = stream; j < dg; j += 16) {
        int p = r0 + j;
        float r = rcsr[p];
        int s = snd[p];
        float dw = 0.f;
        if (r < RMAXf) {
            float tt = r * (NTAB / RMAXf);
            int i = (int)tt; if (i > NTAB - 1) i = NTAB - 1;
            float f = tt - (float)i;
            size_t b = (size_t)i * TROW + 32 + c;
            dw = tab[b] * (1.f - f) + tab[b + TROW] * f;
        }
        float gdr = gst * sc1[spk[p] * CC + c] * dw;
        for (int m = 16; m >= 1; m >>= 1) gdr += __shfl_xor(gdr, m, 64);
        if (c < 3) {
            float4 g4 = geo[p];
            float u = (c == 0) ? g4.y : (c == 1) ? g4.z : g4.w;
            float gv = gvcsr[3 * p + c] + u * gdr;
            atomicAdd(&F[3 * s + c], gv);
            ft -= gv;
        }
    }
    if (c < 3) atomicAdd(&F[3 * wid + c], ft);
}

extern "C" void kernel_launch(void* const* d_in, const int* in_sizes, int n_in,
                              void* d_out, int out_size, void* d_ws, size_t ws_size,
                              hipStream_t stream) {
    const float* pos = (const float*)d_in[0];
    const float* na = (const float*)d_in[1];
    const float* shifts = (const float*)d_in[2];
    const int* ei = (const int*)d_in[3];
    const int* batch = (const int*)d_in[4];
    const float* aE = (const float*)d_in[6];
    const float* Wemb = (const float*)d_in[7];
    const float* Wup1 = (const float*)d_in[8];
    const float* M1a = (const float*)d_in[9];
    const float* M1b = (const float*)d_in[10];
    const float* M1c = (const float*)d_in[11];
    const float* M1d = (const float*)d_in[12];
    const float* Wl1 = (const float*)d_in[13];
    const float* Wprod1 = (const float*)d_in[14];
    const float* Wup2 = (const float*)d_in[15];
    const float* M2a = (const float*)d_in[16];
    const float* M2b = (const float*)d_in[17];
    const float* M2c = (const float*)d_in[18];
    const float* M2d = (const float*)d_in[19];
    const float* Wl2 = (const float*)d_in[20];
    const float* Wprod2 = (const float*)d_in[21];
    const float* Wsc2 = (const float*)d_in[22];
    const float* wr1 = (const float*)d_in[23];
    const float* Wr2a = (const float*)d_in[24];
    const float* wr2b = (const float*)d_in[25];

    float* ws = (float*)d_ws;
    float* tab = ws + OF_TAB;
    float4* geo = (float4*)(ws + OF_GEO);
    int* snd = (int*)(ws + OF_SND);
    int* spk = (int*)(ws + OF_SPK);
    float* rcsr = ws + OF_RCSR;
    float* YE = ws + OF_YE;
    float* sc1 = ws + OF_SC1;
    int* sp = (int*)(ws + OF_SP);
    float* gv = ws + OF_GV;
    float* a0s = ws + OF_A0;
    float* nf1 = ws + OF_NF1;
    float* scal2 = ws + OF_SCAL2;
    float* nep = ws + OF_NEP;
    float* gm2T = ws + OF_GM2T;
    float* gnf1p = ws + OF_GNF1P;
    float* gS1 = ws + OF_GS1;
    int* rows = (int*)(ws + OF_ROWS);
    int* deg = (int*)(ws + OF_DEG);
    int* cur = (int*)(ws + OF_CUR);
    float* gsc2 = ws + OF_GSC2;

    float* out_total = (float*)d_out;
    float* out_ne = out_total + GG;
    float* out_F = out_ne + NN;

    hipMemsetAsync(d_out, 0, sizeof(float) * (GG + NN + 3 * NN), stream);
    hipMemsetAsync(deg, 0, sizeof(float) * (size_t)(OF_END - OF_DEG), stream);

    k_species<<<(NN + 255) / 256, 256, 0, stream>>>(na, sp);
    k_scal1<<<1, 320, 0, stream>>>(Wemb, Wup1, sc1);
    k_table<<<NTAB + 1, 64, 0, stream>>>(M1a, M1b, M1c, M1d, M2a, M2b, M2c, M2d, tab);
    k_deg<<<(NE + 255) / 256, 256, 0, stream>>>(ei, deg);
    k_scan<<<1, 1024, 0, stream>>>(deg, rows, cur);
    k_fill<<<(NE + 255) / 256, 256, 0, stream>>>(pos, shifts, ei, sp, cur, snd, spk, rcsr, geo, YE);
    k_gather1<<<NN, 256, 0, stream>>>(rows, spk, rcsr, sp, sc1, tab, Wl1, Wprod1,
                                      Wup2, wr1, aE, a0s, nf1, scal2, nep);
    k_node2<<<NN, 256, 0, stream>>>(rows, snd, rcsr, YE, sp, scal2, tab, Wl2,
                                    Wprod2, Wsc2, nf1, Wr2a, wr2b, wr1, nep, batch,
                                    gm2T, gnf1p, out_total, out_ne);
    k_gbwd2<<<2 * NN, 256, 0, stream>>>(rows, snd, geo, YE, scal2, tab, gm2T, gsc2, gv);
    k_node_bwd2<<<NN / 8, 256, 0, stream>>>(gnf1p, gsc2, Wup2, a0s, sp, Wprod1, Wl1, gS1);
    k_gbwd1<<<2 * NN, 256, 0, stream>>>(rows, snd, spk, rcsr, geo, sc1, tab, gS1, gv, out_F);
}

// Round 13
// 430.801 us; speedup vs baseline: 1.1519x; 1.1519x over previous
//
#include <hip/hip_runtime.h>
#include <math.h>

#define NN 10000
#define NE 320000
#define KS 10
#define CC 32
#define GG 8
#define NTAB 2048
#define TROW 320
#define RMAXf 5.0f
#define AVGf 32.0f

// ---- workspace layout (float offsets) ----
#define OF_TAB 0
#define SZ_TAB ((NTAB + 1) * TROW)
#define OF_GEO (OF_TAB + SZ_TAB)      /* float4-aligned */
#define OF_SND (OF_GEO + 4 * NE)
#define OF_SPK (OF_SND + NE)
#define OF_RCSR (OF_SPK + NE)
#define OF_YE (OF_RCSR + NE)          /* 16 per edge, float4-aligned */
#define OF_SC1 (OF_YE + 16 * NE)
#define OF_SP (OF_SC1 + KS * CC)
#define OF_GV (OF_SP + NN)            /* CSR-ordered gvec */
#define OF_A0 (OF_GV + 3 * NE)
#define OF_NF1 (OF_A0 + NN * CC)
#define OF_SCAL2 (OF_NF1 + NN * CC)
#define OF_NEP (OF_SCAL2 + NN * CC)
#define OF_GM2T (OF_NEP + NN)
#define OF_GNF1P (OF_GM2T + NN * CC * 16)
#define OF_GS1 (OF_GNF1P + NN * CC)
#define OF_ROWS (OF_GS1 + NN * CC)
// zero-init block:
#define OF_DEG (OF_ROWS + NN + 1)
#define OF_CUR (OF_DEG + NN)
#define OF_GSC2 (OF_CUR + NN)
#define OF_END (OF_GSC2 + NN * CC)

__device__ __forceinline__ int lm_of(int m) { return (m == 0) ? 0 : (m < 4) ? 1 : (m < 9) ? 2 : 3; }

__device__ __forceinline__ void sph16(float x, float y, float z, float* Y) {
    const float s3 = 1.7320508075688772f, s5 = 2.23606797749979f, s15 = 3.872983346207417f,
                s105 = 10.246950765959598f, s358 = 2.091650066335189f,
                s218 = 1.6201851746019651f, s7 = 2.6457513110645907f;
    Y[0] = 1.f;
    Y[1] = s3 * x; Y[2] = s3 * y; Y[3] = s3 * z;
    Y[4] = s15 * x * y; Y[5] = s15 * y * z; Y[6] = 0.5f * s5 * (3.f * z * z - 1.f);
    Y[7] = s15 * x * z; Y[8] = 0.5f * s15 * (x * x - y * y);
    Y[9] = s358 * y * (3.f * x * x - y * y);
    Y[10] = s105 * x * y * z;
    Y[11] = s218 * y * (5.f * z * z - 1.f);
    Y[12] = 0.5f * s7 * z * (5.f * z * z - 3.f);
    Y[13] = s218 * x * (5.f * z * z - 1.f);
    Y[14] = 0.5f * s105 * z * (x * x - y * y);
    Y[15] = s358 * x * (x * x - 3.f * y * y);
}

__device__ __forceinline__ void sph16_grad(float x, float y, float z, float* Dx, float* Dy, float* Dz) {
    const float s3 = 1.7320508075688772f, s5 = 2.23606797749979f, s15 = 3.872983346207417f,
                s105 = 10.246950765959598f, s358 = 2.091650066335189f,
                s218 = 1.6201851746019651f, s7 = 2.6457513110645907f;
    Dx[0] = 0; Dy[0] = 0; Dz[0] = 0;
    Dx[1] = s3; Dy[1] = 0; Dz[1] = 0;
    Dx[2] = 0; Dy[2] = s3; Dz[2] = 0;
    Dx[3] = 0; Dy[3] = 0; Dz[3] = s3;
    Dx[4] = s15 * y; Dy[4] = s15 * x; Dz[4] = 0;
    Dx[5] = 0; Dy[5] = s15 * z; Dz[5] = s15 * y;
    Dx[6] = 0; Dy[6] = 0; Dz[6] = 3.f * s5 * z;
    Dx[7] = s15 * z; Dy[7] = 0; Dz[7] = s15 * x;
    Dx[8] = s15 * x; Dy[8] = -s15 * y; Dz[8] = 0;
    Dx[9] = 6.f * s358 * x * y; Dy[9] = 3.f * s358 * (x * x - y * y); Dz[9] = 0;
    Dx[10] = s105 * y * z; Dy[10] = s105 * x * z; Dz[10] = s105 * x * y;
    Dx[11] = 0; Dy[11] = s218 * (5.f * z * z - 1.f); Dz[11] = 10.f * s218 * y * z;
    Dx[12] = 0; Dy[12] = 0; Dz[12] = 0.5f * s7 * (15.f * z * z - 3.f);
    Dx[13] = s218 * (5.f * z * z - 1.f); Dy[13] = 0; Dz[13] = 10.f * s218 * x * z;
    Dx[14] = s105 * x * z; Dy[14] = -s105 * y * z; Dz[14] = 0.5f * s105 * (x * x - y * y);
    Dx[15] = 3.f * s358 * (x * x - y * y); Dy[15] = -6.f * s358 * x * y; Dz[15] = 0;
}

// -------- species argmax --------
__global__ void k_species(const float* __restrict__ na, int* __restrict__ sp) {
    int n = blockIdx.x * blockDim.x + threadIdx.x;
    if (n >= NN) return;
    int k = 0;
    for (int j = 0; j < KS; j++)
        if (na[n * KS + j] > 0.5f) k = j;
    sp[n] = k;
}

// -------- scal1 table = W_emb @ Wup1 --------
__global__ void k_scal1(const float* __restrict__ Wemb, const float* __restrict__ Wup1, float* __restrict__ st) {
    int i = threadIdx.x;
    if (i >= KS * CC) return;
    int k = i / CC, c = i % CC;
    float s = 0;
    for (int j = 0; j < CC; j++) s += Wemb[k * CC + j] * Wup1[j * CC + c];
    st[i] = s;
}

// -------- radial MLP lookup table (values + d/dr), fp32 MLP (fp64 radial seed) --------
__global__ void k_table(const float* __restrict__ M1a, const float* __restrict__ M1b,
                        const float* __restrict__ M1c, const float* __restrict__ M1d,
                        const float* __restrict__ M2a, const float* __restrict__ M2b,
                        const float* __restrict__ M2c, const float* __restrict__ M2d,
                        float* __restrict__ tab) {
    const double PI = 3.14159265358979323846;
    int row = blockIdx.x;
    int j = threadIdx.x;  // 0..63
    __shared__ float sR[8], sdR[8];
    __shared__ float sA[64], sdA[64], sB[64], sdB[64];
    if (j < 8) {
        double r = (double)row * ((double)RMAXf / NTAB);
        if (r < 1e-6) r = 1e-6;
        double a = (double)(j + 1) * PI / (double)RMAXf;
        double env = 0.0, denv = 0.0;
        if (row < NTAB) {
            double t = r / (double)RMAXf;
            double t4 = t * t * t * t;
            env = 1.0 - 21.0 * t4 * t + 35.0 * t4 * t * t - 15.0 * t4 * t * t * t;
            denv = (-105.0 * t4 + 210.0 * t4 * t - 105.0 * t4 * t * t) / (double)RMAXf;
        }
        double pref = sqrt(2.0 / (double)RMAXf);
        double s = sin(a * r), cg = cos(a * r);
        double bess = pref * s / r;
        double dbess = pref * (a * cg / r - s / (r * r));
        sR[j] = (float)(bess * env);
        sdR[j] = (float)(dbess * env + bess * denv);
    }
    __syncthreads();
    size_t rb = (size_t)row * TROW;

    // ---- MLP1 ----
    {
        float p = 0, dp = 0;
        for (int i = 0; i < 8; i++) { float w = M1a[i * 64 + j]; p += sR[i] * w; dp += sdR[i] * w; }
        float sg = 1.f / (1.f + expf(-p));
        sB[j] = p * sg; sdB[j] = dp * sg * (1.f + p * (1.f - sg));
    }
    __syncthreads();
    {
        float p = 0, dp = 0;
        for (int i = 0; i < 64; i++) { float w = M1b[i * 64 + j]; p += sB[i] * w; dp += sdB[i] * w; }
        float sg = 1.f / (1.f + expf(-p));
        sA[j] = p * sg; sdA[j] = dp * sg * (1.f + p * (1.f - sg));
    }
    __syncthreads();
    {
        float p = 0, dp = 0;
        for (int i = 0; i < 64; i++) { float w = M1c[i * 64 + j]; p += sA[i] * w; dp += sdA[i] * w; }
        float sg = 1.f / (1.f + expf(-p));
        sB[j] = p * sg; sdB[j] = dp * sg * (1.f + p * (1.f - sg));
    }
    __syncthreads();
    #pragma unroll
    for (int t2 = 0; t2 < 2; t2++) {
        int o = j + t2 * 64;
        if ((o & 3) == 0) {
            float p = 0, dp = 0;
            for (int i = 0; i < 64; i++) { float w = M1d[i * 128 + o]; p += sB[i] * w; dp += sdB[i] * w; }
            int c = o >> 2;
            tab[rb + c] = p;
            tab[rb + 32 + c] = dp;
        }
    }
    __syncthreads();

    // ---- MLP2 ----
    {
        float p = 0, dp = 0;
        for (int i = 0; i < 8; i++) { float w = M2a[i * 64 + j]; p += sR[i] * w; dp += sdR[i] * w; }
        float sg = 1.f / (1.f + expf(-p));
        sB[j] = p * sg; sdB[j] = dp * sg * (1.f + p * (1.f - sg));
    }
    __syncthreads();
    {
        float p = 0, dp = 0;
        for (int i = 0; i < 64; i++) { float w = M2b[i * 64 + j]; p += sB[i] * w; dp += sdB[i] * w; }
        float sg = 1.f / (1.f + expf(-p));
        sA[j] = p * sg; sdA[j] = dp * sg * (1.f + p * (1.f - sg));
    }
    __syncthreads();
    {
        float p = 0, dp = 0;
        for (int i = 0; i < 64; i++) { float w = M2c[i * 64 + j]; p += sA[i] * w; dp += sdA[i] * w; }
        float sg = 1.f / (1.f + expf(-p));
        sB[j] = p * sg; sdB[j] = dp * sg * (1.f + p * (1.f - sg));
    }
    __syncthreads();
    #pragma unroll
    for (int t2 = 0; t2 < 2; t2++) {
        int o = j + t2 * 64;
        float p = 0, dp = 0;
        for (int i = 0; i < 64; i++) { float w = M2d[i * 128 + o]; p += sB[i] * w; dp += sdB[i] * w; }
        tab[rb + 64 + o] = p;
        tab[rb + 192 + o] = dp;
    }
}

// -------- rcv degree count only --------
__global__ void k_deg(const int* __restrict__ ei, int* __restrict__ deg) {
    int e = blockIdx.x * 256 + threadIdx.x;
    if (e >= NE) return;
    atomicAdd(&deg[ei[NE + e]], 1);
}

// -------- exclusive scan over NN degree counters (single block, 1024 thr) --------
__global__ void k_scan(const int* __restrict__ deg, int* __restrict__ rows, int* __restrict__ cur) {
    __shared__ int part[1024];
    int t = threadIdx.x;
    const int per = (NN + 1023) / 1024;
    int base = t * per;
    int s = 0;
    for (int i = 0; i < per; i++) {
        int idx = base + i;
        if (idx < NN) s += deg[idx];
    }
    part[t] = s;
    __syncthreads();
    for (int off = 1; off < 1024; off <<= 1) {
        int v = (t >= off) ? part[t - off] : 0;
        __syncthreads();
        part[t] += v;
        __syncthreads();
    }
    int run = (t == 0) ? 0 : part[t - 1];
    for (int i = 0; i < per; i++) {
        int idx = base + i;
        if (idx < NN) {
            rows[idx] = run;
            cur[idx] = run;
            run += deg[idx];
        }
    }
    if (t == 1023) rows[NN] = run;
}

// -------- CSR fill: geometry + packed edge data + per-edge spherical harmonics --------
__global__ void k_fill(const float* __restrict__ pos, const float* __restrict__ shifts,
                       const int* __restrict__ ei, const int* __restrict__ sp,
                       int* __restrict__ cur, int* __restrict__ snd, int* __restrict__ spk,
                       float* __restrict__ rcsr, float4* __restrict__ geo,
                       float* __restrict__ YE) {
    int e = blockIdx.x * 256 + threadIdx.x;
    if (e >= NE) return;
    int s = ei[e], t = ei[NE + e];
    float vx = pos[3 * t] - pos[3 * s] + shifts[3 * e];
    float vy = pos[3 * t + 1] - pos[3 * s + 1] + shifts[3 * e + 1];
    float vz = pos[3 * t + 2] - pos[3 * s + 2] + shifts[3 * e + 2];
    float r = sqrtf(vx * vx + vy * vy + vz * vz + 1e-12f);
    float inv = 1.f / r;
    float ux = vx * inv, uy = vy * inv, uz = vz * inv;
    int p = atomicAdd(&cur[t], 1);
    snd[p] = s;
    spk[p] = sp[s];
    rcsr[p] = r;
    geo[p] = make_float4(r, ux, uy, uz);
    float Y[16];
    sph16(ux, uy, uz, Y);
    float4* yp = (float4*)&YE[(size_t)p * 16];
    yp[0] = make_float4(Y[0], Y[1], Y[2], Y[3]);
    yp[1] = make_float4(Y[4], Y[5], Y[6], Y[7]);
    yp[2] = make_float4(Y[8], Y[9], Y[10], Y[11]);
    yp[3] = make_float4(Y[12], Y[13], Y[14], Y[15]);
}

// -------- layer-1 gather + node mid: one block (4 waves, 8 streams) per node --------
__global__ __launch_bounds__(256, 8)
void k_gather1(const int* __restrict__ rows, const int* __restrict__ spk,
               const float* __restrict__ rcsr, const int* __restrict__ sp,
               const float* __restrict__ sc1, const float* __restrict__ tab,
               const float* __restrict__ Wl1, const float* __restrict__ Wprod1,
               const float* __restrict__ Wup2, const float* __restrict__ wr1,
               const float* __restrict__ aE,
               float* __restrict__ a0s, float* __restrict__ nf1,
               float* __restrict__ scal2, float* __restrict__ nep) {
    __shared__ float red[4][CC];
    int wid = blockIdx.x;
    int tid = threadIdx.x;
    int wv = tid >> 6, lane = tid & 63, c = lane & 31, h = lane >> 5, hb = h << 5;
    int stream = wv * 2 + h;
    int r0 = rows[wid], dg = rows[wid + 1] - r0;
    float acc = 0.f;
    for (int j = stream; j < dg; j += 8) {
        int p = r0 + j;
        float r = rcsr[p];
        float scv = sc1[spk[p] * CC + c];
        float w1 = 0.f;
        if (r < RMAXf) {
            float tt = r * (NTAB / RMAXf);
            int i = (int)tt; if (i > NTAB - 1) i = NTAB - 1;
            float f = tt - (float)i;
            size_t b = (size_t)i * TROW + c;
            w1 = tab[b] * (1.f - f) + tab[b + TROW] * f;
        }
        acc += scv * w1;
    }
    acc += __shfl_xor(acc, 32, 64);
    if (h == 0) red[wv][c] = acc;
    __syncthreads();
    if (wv != 0) return;
    acc = red[0][c] + red[1][c] + red[2][c] + red[3][c];
    float a0 = 0.f;
    for (int d = 0; d < CC; d++) a0 += __shfl(acc, hb + d, 64) * Wl1[d * CC + c];
    a0 *= (1.f / AVGf);
    int k = sp[wid];
    const float* cp = &Wprod1[(k * CC + c) * 3];
    float nf = a0 * (cp[0] + cp[1] * a0 + cp[2] * a0 * a0);
    float s2 = 0.f;
    for (int d = 0; d < CC; d++) s2 += __shfl(nf, hb + d, 64) * Wup2[d * CC + c];
    float t1 = nf * wr1[c];
    for (int m = 16; m >= 1; m >>= 1) t1 += __shfl_xor(t1, m, 64);
    if (h == 0) {
        a0s[wid * CC + c] = a0;
        nf1[wid * CC + c] = nf;
        scal2[wid * CC + c] = s2;
        if (c == 0) nep[wid] = aE[k] + t1;
    }
}

// -------- layer-2 gather (YE) + node phase on wave 0 --------
__global__ __launch_bounds__(256, 8)
void k_node2(const int* __restrict__ rows, const int* __restrict__ snd,
             const float* __restrict__ rcsr, const float* __restrict__ YE,
             const int* __restrict__ sp,
             const float* __restrict__ scal2, const float* __restrict__ tab,
             const float* __restrict__ Wl2, const float* __restrict__ Wprod2,
             const float* __restrict__ Wsc2, const float* __restrict__ nf1,
             const float* __restrict__ Wr2a, const float* __restrict__ wr2b,
             const float* __restrict__ wr1, const float* __restrict__ nep,
             const int* __restrict__ batch,
             float* __restrict__ gm2T, float* __restrict__ gnf1p,
             float* __restrict__ out_total, float* __restrict__ out_ne) {
    __shared__ float lds[4][512];
    int wid = blockIdx.x;
    int tid = threadIdx.x;
    int wv = tid >> 6, lane = tid & 63, c = lane & 31, h = lane >> 5, hb = h << 5;
    int stream = wv * 2 + h;
    int r0 = rows[wid], dg = rows[wid + 1] - r0;

    // ---- pass 1: S2 gather across 8 streams (Y from YE) ----
    float S2r[16];
    #pragma unroll
    for (int m = 0; m < 16; m++) S2r[m] = 0.f;
    for (int j = stream; j < dg; j += 8) {
        int p = r0 + j;
        float r = rcsr[p];
        float sc = scal2[snd[p] * CC + c];
        float scw[4] = {0, 0, 0, 0};
        if (r < RMAXf) {
            float tt = r * (NTAB / RMAXf);
            int i = (int)tt; if (i > NTAB - 1) i = NTAB - 1;
            float f = tt - (float)i;
            size_t b = (size_t)i * TROW + 64 + c * 4;
            float4 t0 = *(const float4*)&tab[b];
            float4 t1 = *(const float4*)&tab[b + TROW];
            scw[0] = sc * (t0.x + (t1.x - t0.x) * f);
            scw[1] = sc * (t0.y + (t1.y - t0.y) * f);
            scw[2] = sc * (t0.z + (t1.z - t0.z) * f);
            scw[3] = sc * (t0.w + (t1.w - t0.w) * f);
        }
        const float4* yp = (const float4*)&YE[(size_t)p * 16];
        float4 y0 = yp[0], y1 = yp[1], y2 = yp[2], y3 = yp[3];
        float Y[16] = {y0.x, y0.y, y0.z, y0.w, y1.x, y1.y, y1.z, y1.w,
                       y2.x, y2.y, y2.z, y2.w, y3.x, y3.y, y3.z, y3.w};
        #pragma unroll
        for (int m = 0; m < 16; m++) S2r[m] += scw[lm_of(m)] * Y[m];
    }
    #pragma unroll
    for (int m = 0; m < 16; m++) S2r[m] += __shfl_xor(S2r[m], 32, 64);
    if (h == 0) {
        #pragma unroll
        for (int m = 0; m < 16; m++) lds[wv][m * 32 + c] = S2r[m];
    }
    __syncthreads();
    for (int idx = tid; idx < 512; idx += 256)
        lds[0][idx] += lds[1][idx] + lds[2][idx] + lds[3][idx];
    __syncthreads();
    if (wv != 0) return;   // node phase is wave-0-only; no barriers below

    // ---- node phase (wave 0, intra-wave LDS ordering only) ----
    int d = c;
    float A2r[16];
    #pragma unroll
    for (int m = 0; m < 16; m++) {
        const float* wl = &Wl2[lm_of(m) * CC * CC];
        float acc = 0;
        for (int cc = 0; cc < CC; cc++) acc += lds[0][m * 32 + cc] * wl[cc * CC + d];
        A2r[m] = acc * (1.f / AVGf);
    }
    float pl[4] = {0, 0, 0, 0};
    #pragma unroll
    for (int m = 0; m < 16; m++) pl[lm_of(m)] += A2r[m] * A2r[m];
    int k = sp[wid];
    const float* c2 = &Wprod2[(k * CC + d) * 4];
    float nf2 = c2[0] * pl[0] + c2[1] * pl[1] + c2[2] * pl[2] + c2[3] * pl[3];
    for (int cc = 0; cc < CC; cc++) nf2 += nf1[wid * CC + cc] * Wsc2[((size_t)k * CC + cc) * CC + d];
    int jj = d & 15;
    float zj = 0;
    for (int dd = 0; dd < CC; dd++) zj += __shfl(nf2, hb + dd, 64) * Wr2a[dd * 16 + jj];
    float sg = 1.f / (1.f + expf(-zj));
    float e2p = (d < 16) ? zj * sg * wr2b[jj] : 0.f;
    float red = e2p;
    for (int m = 16; m >= 1; m >>= 1) red += __shfl_xor(red, m, 64);
    if (h == 0 && d == 0) {
        float ne = nep[wid] + red;
        out_ne[wid] = ne;
        atomicAdd(&out_total[batch[wid]], ne);
    }
    float gz = sg * (1.f + zj * (1.f - sg)) * wr2b[jj];
    float gn = 0;
    for (int j2 = 0; j2 < 16; j2++) gn += Wr2a[d * 16 + j2] * __shfl(gz, hb + j2, 64);
    if (h == 0) {
        #pragma unroll
        for (int m = 0; m < 16; m++) lds[0][m * 32 + d] = 2.f * A2r[m] * gn * c2[lm_of(m)];
    }
    float gmv[16];
    #pragma unroll
    for (int m = 0; m < 16; m++) {
        const float* wl = &Wl2[lm_of(m) * CC * CC + c * CC];
        float acc = 0;
        for (int dd = 0; dd < CC; dd++) acc += lds[0][m * 32 + dd] * wl[dd];
        gmv[m] = acc * (1.f / AVGf);
    }
    float g1 = wr1[c];
    for (int dd = 0; dd < CC; dd++) g1 += __shfl(gn, hb + dd, 64) * Wsc2[((size_t)k * CC + c) * CC + dd];
    if (h == 0) {
        #pragma unroll
        for (int m = 0; m < 16; m++) gm2T[(size_t)wid * 512 + m * 32 + c] = gmv[m];
        gnf1p[wid * CC + c] = g1;
    }
}

// -------- layer-2 backward gather: 4 waves, Y from YE, gvec CSR-ordered --------
__global__ __launch_bounds__(256, 4)
void k_gbwd2(const int* __restrict__ rows, const int* __restrict__ snd,
             const float4* __restrict__ geo, const float* __restrict__ YE,
             const float* __restrict__ scal2, const float* __restrict__ tab,
             const float* __restrict__ gm2T,
             float* __restrict__ gsc2, float* __restrict__ gvcsr) {
    int wid = blockIdx.x;
    int tid = threadIdx.x;
    int wv = tid >> 6, lane = tid & 63, c = lane & 31, h = lane >> 5;
    int stream = wv * 2 + h;
    float gm[16];
    #pragma unroll
    for (int m = 0; m < 16; m++) gm[m] = gm2T[(size_t)wid * 512 + m * 32 + c];
    int r0 = rows[wid], dg = rows[wid + 1] - r0;
    for (int j = stream; j < dg; j += 8) {
        int p = r0 + j;
        float4 g4 = geo[p];
        int s = snd[p];
        float sc = scal2[s * CC + c];
        float r = g4.x, ux = g4.y, uy = g4.z, uz = g4.w;
        float w2[4] = {0, 0, 0, 0}, scw[4] = {0, 0, 0, 0}, sdw[4] = {0, 0, 0, 0};
        if (r < RMAXf) {
            float tt = r * (NTAB / RMAXf);
            int i = (int)tt; if (i > NTAB - 1) i = NTAB - 1;
            float f = tt - (float)i;
            size_t b = (size_t)i * TROW + 64 + c * 4;
            size_t b2 = (size_t)i * TROW + 192 + c * 4;
            float4 t0 = *(const float4*)&tab[b];
            float4 t1 = *(const float4*)&tab[b + TROW];
            float4 d0 = *(const float4*)&tab[b2];
            float4 d1 = *(const float4*)&tab[b2 + TROW];
            w2[0] = t0.x + (t1.x - t0.x) * f; w2[1] = t0.y + (t1.y - t0.y) * f;
            w2[2] = t0.z + (t1.z - t0.z) * f; w2[3] = t0.w + (t1.w - t0.w) * f;
            sdw[0] = sc * (d0.x + (d1.x - d0.x) * f); sdw[1] = sc * (d0.y + (d1.y - d0.y) * f);
            sdw[2] = sc * (d0.z + (d1.z - d0.z) * f); sdw[3] = sc * (d0.w + (d1.w - d0.w) * f);
            scw[0] = sc * w2[0]; scw[1] = sc * w2[1]; scw[2] = sc * w2[2]; scw[3] = sc * w2[3];
        }
        const float4* yp = (const float4*)&YE[(size_t)p * 16];
        float4 y0 = yp[0], y1 = yp[1], y2 = yp[2], y3 = yp[3];
        float Y[16] = {y0.x, y0.y, y0.z, y0.w, y1.x, y1.y, y1.z, y1.w,
                       y2.x, y2.y, y2.z, y2.w, y3.x, y3.y, y3.z, y3.w};
        float Dx[16], Dy[16], Dz[16];
        sph16_grad(ux, uy, uz, Dx, Dy, Dz);
        float gsc = 0, gdr = 0, gx = 0, gy = 0, gz = 0;
        #pragma unroll
        for (int m = 0; m < 16; m++) {
            float g = gm[m];
            int l = lm_of(m);
            float t = g * Y[m];
            gsc += t * w2[l];
            gdr += t * sdw[l];
            float gY = g * scw[l];
            gx += gY * Dx[m]; gy += gY * Dy[m]; gz += gY * Dz[m];
        }
        atomicAdd(&gsc2[s * CC + c], gsc);
        for (int m2 = 16; m2 >= 1; m2 >>= 1) {
            gdr += __shfl_xor(gdr, m2, 64);
            gx += __shfl_xor(gx, m2, 64);
            gy += __shfl_xor(gy, m2, 64);
            gz += __shfl_xor(gz, m2, 64);
        }
        if (c == 0) {
            float inv = 1.f / r;
            float dot = ux * gx + uy * gy + uz * gz;
            gvcsr[3 * p] = ux * gdr + (gx - ux * dot) * inv;
            gvcsr[3 * p + 1] = uy * gdr + (gy - uy * dot) * inv;
            gvcsr[3 * p + 2] = uz * gdr + (gz - uz * dot) * inv;
        }
    }
}

// -------- node bwd2: g_S1 --------
__global__ void k_node_bwd2(const float* __restrict__ gnf1p, const float* __restrict__ gsc2,
                            const float* __restrict__ Wup2, const float* __restrict__ a0s,
                            const int* __restrict__ sp, const float* __restrict__ Wprod1,
                            const float* __restrict__ Wl1, float* __restrict__ gS1) {
    int gid = blockIdx.x * 256 + threadIdx.x;
    int n = gid >> 5, c = gid & 31;
    if (n >= NN) return;
    int hb = threadIdx.x & 32;
    float g1 = gnf1p[n * CC + c];
    for (int dd = 0; dd < CC; dd++) g1 += gsc2[n * CC + dd] * Wup2[c * CC + dd];
    float a0 = a0s[n * CC + c];
    int k = sp[n];
    const float* cp = &Wprod1[(k * CC + c) * 3];
    float ga0 = g1 * (cp[0] + 2.f * cp[1] * a0 + 3.f * cp[2] * a0 * a0);
    float acc = 0;
    for (int dd = 0; dd < CC; dd++) acc += __shfl(ga0, hb + dd, 64) * Wl1[c * CC + dd];
    gS1[n * CC + c] = acc * (1.f / AVGf);
}

// -------- layer-1 backward gather + force scatter (CSR, 4 waves) --------
__global__ __launch_bounds__(256, 8)
void k_gbwd1(const int* __restrict__ rows, const int* __restrict__ snd,
             const int* __restrict__ spk, const float* __restrict__ rcsr,
             const float4* __restrict__ geo, const float* __restrict__ sc1,
             const float* __restrict__ tab, const float* __restrict__ gS1,
             const float* __restrict__ gvcsr, float* __restrict__ F) {
    int wid = blockIdx.x;
    int tid = threadIdx.x;
    int wv = tid >> 6, lane = tid & 63, c = lane & 31, h = lane >> 5;
    int stream = wv * 2 + h;
    int r0 = rows[wid], dg = rows[wid + 1] - r0;
    float gst = gS1[wid * CC + c];
    float ft = 0.f;
    for (int j = stream; j < dg; j += 8) {
        int p = r0 + j;
        float r = rcsr[p];
        int s = snd[p];
        float dw = 0.f;
        if (r < RMAXf) {
            float tt = r * (NTAB / RMAXf);
            int i = (int)tt; if (i > NTAB - 1) i = NTAB - 1;
            float f = tt - (float)i;
            size_t b = (size_t)i * TROW + 32 + c;
            dw = tab[b] * (1.f - f) + tab[b + TROW] * f;
        }
        float gdr = gst * sc1[spk[p] * CC + c] * dw;
        for (int m = 16; m >= 1; m >>= 1) gdr += __shfl_xor(gdr, m, 64);
        if (c < 3) {
            float4 g4 = geo[p];
            float u = (c == 0) ? g4.y : (c == 1) ? g4.z : g4.w;
            float gv = gvcsr[3 * p + c] + u * gdr;
            atomicAdd(&F[3 * s + c], gv);
            ft -= gv;
        }
    }
    if (c < 3) atomicAdd(&F[3 * wid + c], ft);
}

extern "C" void kernel_launch(void* const* d_in, const int* in_sizes, int n_in,
                              void* d_out, int out_size, void* d_ws, size_t ws_size,
                              hipStream_t stream) {
    const float* pos = (const float*)d_in[0];
    const float* na = (const float*)d_in[1];
    const float* shifts = (const float*)d_in[2];
    const int* ei = (const int*)d_in[3];
    const int* batch = (const int*)d_in[4];
    const float* aE = (const float*)d_in[6];
    const float* Wemb = (const float*)d_in[7];
    const float* Wup1 = (const float*)d_in[8];
    const float* M1a = (const float*)d_in[9];
    const float* M1b = (const float*)d_in[10];
    const float* M1c = (const float*)d_in[11];
    const float* M1d = (const float*)d_in[12];
    const float* Wl1 = (const float*)d_in[13];
    const float* Wprod1 = (const float*)d_in[14];
    const float* Wup2 = (const float*)d_in[15];
    const float* M2a = (const float*)d_in[16];
    const float* M2b = (const float*)d_in[17];
    const float* M2c = (const float*)d_in[18];
    const float* M2d = (const float*)d_in[19];
    const float* Wl2 = (const float*)d_in[20];
    const float* Wprod2 = (const float*)d_in[21];
    const float* Wsc2 = (const float*)d_in[22];
    const float* wr1 = (const float*)d_in[23];
    const float* Wr2a = (const float*)d_in[24];
    const float* wr2b = (const float*)d_in[25];

    float* ws = (float*)d_ws;
    float* tab = ws + OF_TAB;
    float4* geo = (float4*)(ws + OF_GEO);
    int* snd = (int*)(ws + OF_SND);
    int* spk = (int*)(ws + OF_SPK);
    float* rcsr = ws + OF_RCSR;
    float* YE = ws + OF_YE;
    float* sc1 = ws + OF_SC1;
    int* sp = (int*)(ws + OF_SP);
    float* gv = ws + OF_GV;
    float* a0s = ws + OF_A0;
    float* nf1 = ws + OF_NF1;
    float* scal2 = ws + OF_SCAL2;
    float* nep = ws + OF_NEP;
    float* gm2T = ws + OF_GM2T;
    float* gnf1p = ws + OF_GNF1P;
    float* gS1 = ws + OF_GS1;
    int* rows = (int*)(ws + OF_ROWS);
    int* deg = (int*)(ws + OF_DEG);
    int* cur = (int*)(ws + OF_CUR);
    float* gsc2 = ws + OF_GSC2;

    float* out_total = (float*)d_out;
    float* out_ne = out_total + GG;
    float* out_F = out_ne + NN;

    hipMemsetAsync(d_out, 0, sizeof(float) * (GG + NN + 3 * NN), stream);
    hipMemsetAsync(deg, 0, sizeof(float) * (size_t)(OF_END - OF_DEG), stream);

    k_species<<<(NN + 255) / 256, 256, 0, stream>>>(na, sp);
    k_scal1<<<1, 320, 0, stream>>>(Wemb, Wup1, sc1);
    k_table<<<NTAB + 1, 64, 0, stream>>>(M1a, M1b, M1c, M1d, M2a, M2b, M2c, M2d, tab);
    k_deg<<<(NE + 255) / 256, 256, 0, stream>>>(ei, deg);
    k_scan<<<1, 1024, 0, stream>>>(deg, rows, cur);
    k_fill<<<(NE + 255) / 256, 256, 0, stream>>>(pos, shifts, ei, sp, cur, snd, spk, rcsr, geo, YE);
    k_gather1<<<NN, 256, 0, stream>>>(rows, spk, rcsr, sp, sc1, tab, Wl1, Wprod1,
                                      Wup2, wr1, aE, a0s, nf1, scal2, nep);
    k_node2<<<NN, 256, 0, stream>>>(rows, snd, rcsr, YE, sp, scal2, tab, Wl2,
                                    Wprod2, Wsc2, nf1, Wr2a, wr2b, wr1, nep, batch,
                                    gm2T, gnf1p, out_total, out_ne);
    k_gbwd2<<<NN, 256, 0, stream>>>(rows, snd, geo, YE, scal2, tab, gm2T, gsc2, gv);
    k_node_bwd2<<<NN / 8, 256, 0, stream>>>(gnf1p, gsc2, Wup2, a0s, sp, Wprod1, Wl1, gS1);
    k_gbwd1<<<NN, 256, 0, stream>>>(rows, snd, spk, rcsr, geo, sc1, tab, gS1, gv, out_F);
}